// Round 9
// baseline (119.025 us; speedup 1.0000x reference)
//
#include <hip/hip_runtime.h>

#define Bb 4
#define Qn 256
#define Kn 1024
#define Hn 128
#define QT 4  // q-rows per fused block

// Projections pre-scaled by 2*log2(e) and exponentiated: Eq=2^(s*qp), Ek=2^(s*kp)
// => e^{2(qp+kp)} = Eq*Ek, and tanh(qp+kp) = 1 - 2/(1+Eq*Ek).
constexpr float SCALE = 2.88539008177792681f;  // 2*log2(e)

#if __has_builtin(__builtin_amdgcn_exp2f)
#define EXP2F(x) __builtin_amdgcn_exp2f(x)
#else
#define EXP2F(x) exp2f(x)
#endif
#if __has_builtin(__builtin_amdgcn_rcpf)
#define RCPF(x) __builtin_amdgcn_rcpf(x)
#else
#define RCPF(x) (1.0f / (x))
#endif

// ---------------------------------------------------------------------------
// K1: fused projections. Blocks [0, Bb*Qn/4): query -> EqT (TRANSPOSED
// [b,h,q], so the fused kernel can s_load 4 q-values per h from a uniform
// address). Blocks [Bb*Qn/4, ...): key -> EkT ([b,h,k]). Both exp2-scaled.
// Thread tid holds the 4 row-projections at h=tid -> one float4 store each.
// ---------------------------------------------------------------------------
__global__ __launch_bounds__(128) void proj_kernel(const float* __restrict__ query,
                                                   const float* __restrict__ key,
                                                   const float* __restrict__ Wq,
                                                   const float* __restrict__ Wk,
                                                   float* __restrict__ eqT,
                                                   float* __restrict__ ekT) {
    __shared__ float4 xs[128];  // 4 rows x 32 float4
    const int tid = threadIdx.x;
    const bool isQ = blockIdx.x < (Bb * Qn / 4);
    const int r0 = (isQ ? blockIdx.x : blockIdx.x - Bb * Qn / 4) * 4;
    const float* x = isQ ? query : key;
    const float* W = isQ ? Wq : Wk;

    xs[tid] = ((const float4*)(x + (size_t)r0 * Hn))[tid];
    __syncthreads();
    const float4* W4 = (const float4*)W + (size_t)tid * (Hn / 4);
    float acc0 = 0.f, acc1 = 0.f, acc2 = 0.f, acc3 = 0.f;
#pragma unroll 8
    for (int d = 0; d < Hn / 4; ++d) {
        float4 w = W4[d];
        float4 a0 = xs[d];
        float4 a1 = xs[32 + d];
        float4 a2 = xs[64 + d];
        float4 a3 = xs[96 + d];
        acc0 = fmaf(w.x, a0.x, fmaf(w.y, a0.y, fmaf(w.z, a0.z, fmaf(w.w, a0.w, acc0))));
        acc1 = fmaf(w.x, a1.x, fmaf(w.y, a1.y, fmaf(w.z, a1.z, fmaf(w.w, a1.w, acc1))));
        acc2 = fmaf(w.x, a2.x, fmaf(w.y, a2.y, fmaf(w.z, a2.z, fmaf(w.w, a2.w, acc2))));
        acc3 = fmaf(w.x, a3.x, fmaf(w.y, a3.y, fmaf(w.z, a3.z, fmaf(w.w, a3.w, acc3))));
    }
    float4 res = make_float4(EXP2F(acc0 * SCALE), EXP2F(acc1 * SCALE),
                             EXP2F(acc2 * SCALE), EXP2F(acc3 * SCALE));
    if (isQ) {
        const int b = r0 / Qn;
        const int q0 = r0 % Qn;
        ((float4*)eqT)[((size_t)b * Hn + tid) * (Qn / 4) + (q0 >> 2)] = res;
    } else {
        const int b = r0 / Kn;
        const int k0 = r0 % Kn;
        ((float4*)ekT)[((size_t)b * Hn + tid) * (Kn / 4) + (k0 >> 2)] = res;
    }
}

// ---------------------------------------------------------------------------
// K2: fused score + softmax + context. Block = 1024 thr, (b, QT=4 q-rows).
// Grid = 256 blocks = 1/CU. vs R8: phase A's block-uniform operands (Eq of
// the 4 q-rows, v[h]) are read from GLOBAL at uniform addresses -> compiler
// emits s_load into SGPRs -> ZERO LDS traffic in the inner loop. Per h per
// thread: 1 coalesced global dword (Ek) + 12 VALU (4x fma/rcp/fma).
// mask skipped: -1e-9*(1-mask) perturbs weights by ~1e-12.
// ---------------------------------------------------------------------------
__global__ __launch_bounds__(1024) void fused_attn_kernel(const float* __restrict__ eqT,
                                                          const float* __restrict__ ekT,
                                                          const float* __restrict__ v,
                                                          const float* __restrict__ value,
                                                          float* __restrict__ attn,
                                                          float* __restrict__ ctx) {
    const int tid = threadIdx.x;
    const int q0 = blockIdx.x * QT;
    const int b = blockIdx.y;

    __shared__ __align__(16) float sc[QT][Kn];          // weights (16 KB)
    __shared__ float red[16][QT];                       // per-wave partials
    __shared__ __align__(16) float4 pl[8][QT][Hn / 4];  // ctx partials (16 KB)

    // ---- phase A: thread = k, 4 q-chains; Eq/v scalar, Ek per-lane ----
    const int k = tid;
    const float4* eqb = (const float4*)(eqT + (size_t)b * Hn * Qn) + (q0 >> 2);
    const float* ekb = ekT + (size_t)b * Hn * Kn + k;
    float a0 = 0.f, a1 = 0.f, a2 = 0.f, a3 = 0.f;
#pragma unroll 8
    for (int h = 0; h < Hn; ++h) {
        const float4 qv = eqb[(size_t)h * (Qn / 4)];  // uniform -> s_load_dwordx4
        const float vh = v[h];                        // uniform -> s_load_dword
        const float kv = ekb[(size_t)h * Kn];         // per-lane, coalesced
        float r;
        r = RCPF(fmaf(qv.x, kv, 1.0f)); a0 = fmaf(vh, r, a0);
        r = RCPF(fmaf(qv.y, kv, 1.0f)); a1 = fmaf(vh, r, a1);
        r = RCPF(fmaf(qv.z, kv, 1.0f)); a2 = fmaf(vh, r, a2);
        r = RCPF(fmaf(qv.w, kv, 1.0f)); a3 = fmaf(vh, r, a3);
    }

    // ---- phase B: softmax (score = V - 2a, shift-invariant -> min-reduce a)
    const int lane = tid & 63, wv = tid >> 6;  // 16 waves
    float m0 = a0, m1 = a1, m2 = a2, m3 = a3;
#pragma unroll
    for (int off = 32; off; off >>= 1) {
        m0 = fminf(m0, __shfl_xor(m0, off));
        m1 = fminf(m1, __shfl_xor(m1, off));
        m2 = fminf(m2, __shfl_xor(m2, off));
        m3 = fminf(m3, __shfl_xor(m3, off));
    }
    if (lane == 0) {
        red[wv][0] = m0; red[wv][1] = m1; red[wv][2] = m2; red[wv][3] = m3;
    }
    __syncthreads();
    m0 = red[0][0]; m1 = red[0][1]; m2 = red[0][2]; m3 = red[0][3];
#pragma unroll
    for (int w = 1; w < 16; ++w) {
        m0 = fminf(m0, red[w][0]); m1 = fminf(m1, red[w][1]);
        m2 = fminf(m2, red[w][2]); m3 = fminf(m3, red[w][3]);
    }
    __syncthreads();  // red reused for sums

    float e0 = EXP2F((m0 - a0) * SCALE);
    float e1 = EXP2F((m1 - a1) * SCALE);
    float e2 = EXP2F((m2 - a2) * SCALE);
    float e3 = EXP2F((m3 - a3) * SCALE);
    float s0 = e0, s1 = e1, s2 = e2, s3 = e3;
#pragma unroll
    for (int off = 32; off; off >>= 1) {
        s0 += __shfl_xor(s0, off);
        s1 += __shfl_xor(s1, off);
        s2 += __shfl_xor(s2, off);
        s3 += __shfl_xor(s3, off);
    }
    if (lane == 0) {
        red[wv][0] = s0; red[wv][1] = s1; red[wv][2] = s2; red[wv][3] = s3;
    }
    __syncthreads();
    s0 = red[0][0]; s1 = red[0][1]; s2 = red[0][2]; s3 = red[0][3];
#pragma unroll
    for (int w = 1; w < 16; ++w) {
        s0 += red[w][0]; s1 += red[w][1]; s2 += red[w][2]; s3 += red[w][3];
    }

    const float w0 = e0 * RCPF(s0);
    const float w1 = e1 * RCPF(s1);
    const float w2 = e2 * RCPF(s2);
    const float w3 = e3 * RCPF(s3);
    sc[0][k] = w0; sc[1][k] = w1; sc[2][k] = w2; sc[3][k] = w3;
    float* arow = attn + ((size_t)b * Qn + q0) * Kn + k;
    arow[0 * Kn] = w0; arow[1 * Kn] = w1; arow[2 * Kn] = w2; arow[3 * Kn] = w3;
    __syncthreads();

    // ---- phase C: context. thread = (kc = tid>>7, q = (tid>>5)&3, h4 = tid&31)
    const int kc = tid >> 7;        // 0..7: k in [kc*128, +128)
    const int cq = (tid >> 5) & 3;  // q row
    const int h4 = tid & 31;        // float4 index over h
    const float4* vb = (const float4*)(value + ((size_t)b * Kn + kc * 128) * Hn) + h4;
    const float* wr = &sc[cq][kc * 128];
    float4 acc = make_float4(0.f, 0.f, 0.f, 0.f);
#pragma unroll 4
    for (int kk = 0; kk < 128; ++kk) {
        const float wgt = wr[kk];
        const float4 vv = vb[(size_t)kk * (Hn / 4)];
        acc.x = fmaf(wgt, vv.x, acc.x);
        acc.y = fmaf(wgt, vv.y, acc.y);
        acc.z = fmaf(wgt, vv.z, acc.z);
        acc.w = fmaf(wgt, vv.w, acc.w);
    }
    pl[kc][cq][h4] = acc;
    __syncthreads();
    if (tid < QT * Hn / 4) {  // 128 threads
        const int q = tid >> 5, h = tid & 31;
        float4 r0 = pl[0][q][h], r1 = pl[1][q][h], r2 = pl[2][q][h], r3 = pl[3][q][h];
        float4 r4 = pl[4][q][h], r5 = pl[5][q][h], r6 = pl[6][q][h], r7 = pl[7][q][h];
        float4 sum;
        sum.x = ((r0.x + r1.x) + (r2.x + r3.x)) + ((r4.x + r5.x) + (r6.x + r7.x));
        sum.y = ((r0.y + r1.y) + (r2.y + r3.y)) + ((r4.y + r5.y) + (r6.y + r7.y));
        sum.z = ((r0.z + r1.z) + (r2.z + r3.z)) + ((r4.z + r5.z) + (r6.z + r7.z));
        sum.w = ((r0.w + r1.w) + (r2.w + r3.w)) + ((r4.w + r5.w) + (r6.w + r7.w));
        ((float4*)(ctx + ((size_t)b * Qn + q0 + q) * Hn))[h] = sum;
    }
}

// ---------------------------------------------------------------------------
extern "C" void kernel_launch(void* const* d_in, const int* in_sizes, int n_in,
                              void* d_out, int out_size, void* d_ws, size_t ws_size,
                              hipStream_t stream) {
    const float* query = (const float*)d_in[0];  // (4,256,128)
    const float* key = (const float*)d_in[1];    // (4,1024,128)
    const float* value = (const float*)d_in[2];  // (4,1024,128)
    // d_in[3] = mask: unused (NEG_MASK_SCALE = -1e-9 -> effect ~1e-12)
    const float* Wq = (const float*)d_in[4];
    const float* Wk = (const float*)d_in[5];
    const float* v = (const float*)d_in[6];

    float* out = (float*)d_out;
    float* attn = out;                        // B*Q*K floats
    float* ctx = out + (size_t)Bb * Qn * Kn;  // B*Q*H floats

    float* ws = (float*)d_ws;
    float* eqT = ws;            // 131072 floats: exp2(SCALE*qp), [b,h,q]
    float* ekT = ws + 131072;   // 524288 floats: exp2(SCALE*kp), [b,h,k]

    proj_kernel<<<dim3(Bb * Qn / 4 + Bb * Kn / 4), dim3(128), 0, stream>>>(
        query, key, Wq, Wk, eqT, ekT);
    fused_attn_kernel<<<dim3(Qn / QT, Bb), dim3(1024), 0, stream>>>(
        eqT, ekT, v, value, attn, ctx);
}

// Round 10
// 118.097 us; speedup vs baseline: 1.0079x; 1.0079x over previous
//
#include <hip/hip_runtime.h>

#define Bb 4
#define Qn 256
#define Kn 1024
#define Hn 128
#define QT 4  // q-rows per fused block
#define PF 8  // prefetch depth (float4 ekT loads in flight)

// Projections pre-scaled by 2*log2(e) and exponentiated: Eq=2^(s*qp), Ek=2^(s*kp)
// => e^{2(qp+kp)} = Eq*Ek, and tanh(qp+kp) = 1 - 2/(1+Eq*Ek).
constexpr float SCALE = 2.88539008177792681f;  // 2*log2(e)

#if __has_builtin(__builtin_amdgcn_exp2f)
#define EXP2F(x) __builtin_amdgcn_exp2f(x)
#else
#define EXP2F(x) exp2f(x)
#endif
#if __has_builtin(__builtin_amdgcn_rcpf)
#define RCPF(x) __builtin_amdgcn_rcpf(x)
#else
#define RCPF(x) (1.0f / (x))
#endif

// ---------------------------------------------------------------------------
// K1: fused projections. Blocks [0, Bb*Qn/4): query -> EqT ([b,h,q]).
// Blocks [Bb*Qn/4, ...): key -> EkT ([b,h,k]). Both exp2-scaled.
// ---------------------------------------------------------------------------
__global__ __launch_bounds__(128) void proj_kernel(const float* __restrict__ query,
                                                   const float* __restrict__ key,
                                                   const float* __restrict__ Wq,
                                                   const float* __restrict__ Wk,
                                                   float* __restrict__ eqT,
                                                   float* __restrict__ ekT) {
    __shared__ float4 xs[128];  // 4 rows x 32 float4
    const int tid = threadIdx.x;
    const bool isQ = blockIdx.x < (Bb * Qn / 4);
    const int r0 = (isQ ? blockIdx.x : blockIdx.x - Bb * Qn / 4) * 4;
    const float* x = isQ ? query : key;
    const float* W = isQ ? Wq : Wk;

    xs[tid] = ((const float4*)(x + (size_t)r0 * Hn))[tid];
    __syncthreads();
    const float4* W4 = (const float4*)W + (size_t)tid * (Hn / 4);
    float acc0 = 0.f, acc1 = 0.f, acc2 = 0.f, acc3 = 0.f;
#pragma unroll 8
    for (int d = 0; d < Hn / 4; ++d) {
        float4 w = W4[d];
        float4 a0 = xs[d];
        float4 a1 = xs[32 + d];
        float4 a2 = xs[64 + d];
        float4 a3 = xs[96 + d];
        acc0 = fmaf(w.x, a0.x, fmaf(w.y, a0.y, fmaf(w.z, a0.z, fmaf(w.w, a0.w, acc0))));
        acc1 = fmaf(w.x, a1.x, fmaf(w.y, a1.y, fmaf(w.z, a1.z, fmaf(w.w, a1.w, acc1))));
        acc2 = fmaf(w.x, a2.x, fmaf(w.y, a2.y, fmaf(w.z, a2.z, fmaf(w.w, a2.w, acc2))));
        acc3 = fmaf(w.x, a3.x, fmaf(w.y, a3.y, fmaf(w.z, a3.z, fmaf(w.w, a3.w, acc3))));
    }
    float4 res = make_float4(EXP2F(acc0 * SCALE), EXP2F(acc1 * SCALE),
                             EXP2F(acc2 * SCALE), EXP2F(acc3 * SCALE));
    if (isQ) {
        const int b = r0 / Qn;
        const int q0 = r0 % Qn;
        ((float4*)eqT)[((size_t)b * Hn + tid) * (Qn / 4) + (q0 >> 2)] = res;
    } else {
        const int b = r0 / Kn;
        const int k0 = r0 % Kn;
        ((float4*)ekT)[((size_t)b * Hn + tid) * (Kn / 4) + (k0 >> 2)] = res;
    }
}

// ---------------------------------------------------------------------------
// K2: fused score + softmax + context. Block = 1024 thr, (b, QT=4 q-rows).
// Grid = 256 blocks = 1/CU. vs R9: phase A re-shaped so thread = (q wave-
// uniform, 4 consecutive k) with ONE coalesced float4 ekT load per h feeding
// 12 VALU ops, and an EXPLICIT 8-deep statically-indexed prefetch rotation
// (pf[8], fully unrolled) -> 384 cy of compute between a load's issue and
// use, hiding L2 latency by construction (compiler left only ~2 in flight).
// mask skipped: -1e-9*(1-mask) perturbs weights by ~1e-12.
// ---------------------------------------------------------------------------
__global__ __launch_bounds__(1024) void fused_attn_kernel(const float* __restrict__ eqT,
                                                          const float* __restrict__ ekT,
                                                          const float* __restrict__ v,
                                                          const float* __restrict__ value,
                                                          float* __restrict__ attn,
                                                          float* __restrict__ ctx) {
    const int tid = threadIdx.x;
    const int q0 = blockIdx.x * QT;
    const int b = blockIdx.y;

    __shared__ __align__(16) float sc[QT][Kn];          // weights (16 KB)
    __shared__ float red[16][2];                        // per-wave partials
    __shared__ __align__(16) float4 pl[8][QT][Hn / 4];  // ctx partials (16 KB)

    // ---- phase A: thread = (q = tid>>8 wave-uniform, k-group kg = tid&255) ----
    const int kg = tid & 255;  // k = 4*kg .. 4*kg+3
    const int qu = __builtin_amdgcn_readfirstlane(tid >> 8);  // 0..3, SGPR
    const float4* ekp = (const float4*)(ekT + (size_t)b * Hn * Kn) + kg;
    const float* eqs = eqT + (size_t)b * Hn * Qn + q0 + qu;

    float4 pf[PF];
#pragma unroll
    for (int j = 0; j < PF; ++j) pf[j] = ekp[(size_t)j * (Kn / 4)];

    float a0 = 0.f, a1 = 0.f, a2 = 0.f, a3 = 0.f;
    for (int c = 0; c < Hn / PF; ++c) {
#pragma unroll
        for (int j = 0; j < PF; ++j) {
            const int h = c * PF + j;
            const float4 kv = pf[j];
            if (c < Hn / PF - 1) pf[j] = ekp[(size_t)(h + PF) * (Kn / 4)];
            const float qe = eqs[(size_t)h * Qn];  // wave-uniform -> s_load
            const float vh = v[h];                 // uniform -> s_load
            float r;
            r = RCPF(fmaf(qe, kv.x, 1.0f)); a0 = fmaf(vh, r, a0);
            r = RCPF(fmaf(qe, kv.y, 1.0f)); a1 = fmaf(vh, r, a1);
            r = RCPF(fmaf(qe, kv.z, 1.0f)); a2 = fmaf(vh, r, a2);
            r = RCPF(fmaf(qe, kv.w, 1.0f)); a3 = fmaf(vh, r, a3);
        }
    }

    // ---- phase B: softmax (score = V - 2a, shift-invariant -> min-reduce a)
    const int lane = tid & 63, wv = tid >> 6;  // 16 waves; waves [4q, 4q+4) share q
    float mn = fminf(fminf(a0, a1), fminf(a2, a3));
#pragma unroll
    for (int off = 32; off; off >>= 1) mn = fminf(mn, __shfl_xor(mn, off));
    if (lane == 0) red[wv][0] = mn;
    __syncthreads();
    mn = fminf(fminf(red[qu * 4][0], red[qu * 4 + 1][0]),
               fminf(red[qu * 4 + 2][0], red[qu * 4 + 3][0]));

    const float e0 = EXP2F((mn - a0) * SCALE);
    const float e1 = EXP2F((mn - a1) * SCALE);
    const float e2 = EXP2F((mn - a2) * SCALE);
    const float e3 = EXP2F((mn - a3) * SCALE);
    float s = (e0 + e1) + (e2 + e3);
#pragma unroll
    for (int off = 32; off; off >>= 1) s += __shfl_xor(s, off);
    if (lane == 0) red[wv][1] = s;
    __syncthreads();
    s = (red[qu * 4][1] + red[qu * 4 + 1][1]) +
        (red[qu * 4 + 2][1] + red[qu * 4 + 3][1]);
    const float inv = RCPF(s);

    const float4 w4 = make_float4(e0 * inv, e1 * inv, e2 * inv, e3 * inv);
    ((float4*)&sc[qu][0])[kg] = w4;
    ((float4*)(attn + ((size_t)b * Qn + q0 + qu) * Kn))[kg] = w4;
    __syncthreads();

    // ---- phase C: context. thread = (kc = tid>>7, q = (tid>>5)&3, h4 = tid&31)
    const int kc = tid >> 7;        // 0..7: k in [kc*128, +128)
    const int cq = (tid >> 5) & 3;  // q row
    const int h4 = tid & 31;        // float4 index over h
    const float4* vb = (const float4*)(value + ((size_t)b * Kn + kc * 128) * Hn) + h4;
    const float* wr = &sc[cq][kc * 128];
    float4 acc = make_float4(0.f, 0.f, 0.f, 0.f);
#pragma unroll 4
    for (int kk = 0; kk < 128; ++kk) {
        const float wgt = wr[kk];
        const float4 vv = vb[(size_t)kk * (Hn / 4)];
        acc.x = fmaf(wgt, vv.x, acc.x);
        acc.y = fmaf(wgt, vv.y, acc.y);
        acc.z = fmaf(wgt, vv.z, acc.z);
        acc.w = fmaf(wgt, vv.w, acc.w);
    }
    pl[kc][cq][h4] = acc;
    __syncthreads();
    if (tid < QT * Hn / 4) {  // 128 threads
        const int q = tid >> 5, h = tid & 31;
        float4 r0 = pl[0][q][h], r1 = pl[1][q][h], r2 = pl[2][q][h], r3 = pl[3][q][h];
        float4 r4 = pl[4][q][h], r5 = pl[5][q][h], r6 = pl[6][q][h], r7 = pl[7][q][h];
        float4 sum;
        sum.x = ((r0.x + r1.x) + (r2.x + r3.x)) + ((r4.x + r5.x) + (r6.x + r7.x));
        sum.y = ((r0.y + r1.y) + (r2.y + r3.y)) + ((r4.y + r5.y) + (r6.y + r7.y));
        sum.z = ((r0.z + r1.z) + (r2.z + r3.z)) + ((r4.z + r5.z) + (r6.z + r7.z));
        sum.w = ((r0.w + r1.w) + (r2.w + r3.w)) + ((r4.w + r5.w) + (r6.w + r7.w));
        ((float4*)(ctx + ((size_t)b * Qn + q0 + q) * Hn))[h] = sum;
    }
}

// ---------------------------------------------------------------------------
extern "C" void kernel_launch(void* const* d_in, const int* in_sizes, int n_in,
                              void* d_out, int out_size, void* d_ws, size_t ws_size,
                              hipStream_t stream) {
    const float* query = (const float*)d_in[0];  // (4,256,128)
    const float* key = (const float*)d_in[1];    // (4,1024,128)
    const float* value = (const float*)d_in[2];  // (4,1024,128)
    // d_in[3] = mask: unused (NEG_MASK_SCALE = -1e-9 -> effect ~1e-12)
    const float* Wq = (const float*)d_in[4];
    const float* Wk = (const float*)d_in[5];
    const float* v = (const float*)d_in[6];

    float* out = (float*)d_out;
    float* attn = out;                        // B*Q*K floats
    float* ctx = out + (size_t)Bb * Qn * Kn;  // B*Q*H floats

    float* ws = (float*)d_ws;
    float* eqT = ws;            // 131072 floats: exp2(SCALE*qp), [b,h,q]
    float* ekT = ws + 131072;   // 524288 floats: exp2(SCALE*kp), [b,h,k]

    proj_kernel<<<dim3(Bb * Qn / 4 + Bb * Kn / 4), dim3(128), 0, stream>>>(
        query, key, Wq, Wk, eqT, ekT);
    fused_attn_kernel<<<dim3(Qn / QT, Bb), dim3(1024), 0, stream>>>(
        eqT, ekT, v, value, attn, ctx);
}